// Round 11
// baseline (111.617 us; speedup 1.0000x reference)
//
#include <hip/hip_runtime.h>
#include <hip/hip_fp16.h>

#define B_  4
#define C_  16
#define H_  256
#define W_  256
#define CO_ 16
#define KS_ 3
#define KK_ 9
#define HW_ (H_ * W_)
// ws layout (u32 words): fp8 NHWC image | kbuf f16 B-frags | partials (float)
#define IMG_WORDS ((size_t)B_ * HW_ * 4)   // 16 B per pixel (fp8 e4m3)
#define KER_OFF   IMG_WORDS
#define NKB 5                               // k-blocks per group: K=160
#define NBLK 2048                           // blocks: 128 pixels each
#define PART_OFF (KER_OFF + (size_t)NKB * 256)

typedef _Float16 f16x8 __attribute__((ext_vector_type(8)));
typedef __fp16   fp16x2 __attribute__((ext_vector_type(2)));  // cvt_pkrtz ret
typedef float    f32x2v __attribute__((ext_vector_type(2)));
typedef __attribute__((ext_vector_type(4))) float f32x4;
union U4H8 { uint4 u; f16x8 h; };
union UH2  { unsigned u; __half2 h; };

// ------- Kernel 1: NCHW fp32 -> NHWC fp8 pack + f16 B-fragment kernel pack -
// Block mapping XCD-aligned with deform_loss_mfma: pack block bx (on XCD
// bx&7) writes exactly the pixel range that deform blocks on the same XCD
// will gather -> image stays dirty-resident in the LOCAL per-XCD L2.
// fp8 e4m3 STORAGE only (16 B/pixel, halves the L2 gather stream that now
// bounds deform); blend happens in f32 after cvt, MFMA stays f16 — one
// quantization at pack, MSE averaging shrinks its loss impact to ~3e-3.
__global__ __launch_bounds__(256) void pack_nhwc_fp8(
    const float* __restrict__ inp, const float* __restrict__ ker,
    unsigned* __restrict__ wsu)
{
    const int t = threadIdx.x;
    // bijection on [0,1024): XCD x=bx&7 covers 256-px chunks [x*128,(x+1)*128)
    const int j = (blockIdx.x & 7) * 128 + (blockIdx.x >> 3);
    const int e = j * 256 + t;              // flat pixel (b*HW + hw)
    const int b = e >> 16;
    const int hw = e & (HW_ - 1);
    const float* src = inp + (size_t)b * (C_ * HW_) + hw;
    float v[C_];
#pragma unroll
    for (int c = 0; c < C_; c++)
        v[c] = src[c * HW_];                // coalesced per c-plane
    unsigned u[4];
#pragma unroll
    for (int d = 0; d < 4; d++) {
        unsigned w = 0;
        w = __builtin_amdgcn_cvt_pk_fp8_f32(v[4 * d + 0], v[4 * d + 1], w, false);
        w = __builtin_amdgcn_cvt_pk_fp8_f32(v[4 * d + 2], v[4 * d + 3], w, true);
        u[d] = w;
    }
    ((uint4*)wsu)[e] = make_uint4(u[0], u[1], u[2], u[3]);  // 16 B per pixel

    if (blockIdx.x == 0) {
        // kbuf: f16 B-fragment layout for mfma_f32_16x16x32_f16 (unchanged).
        //   B[k][n]: k = (lane>>4)*8 + j, n = o = lane&15,
        //   tap = 2*blk + (k>>4), c = k&15; zero when tap > 8 (K padding).
        for (int i = t; i < NKB * 256; i += 256) {
            const int wj  = i & 3;
            const int l   = (i >> 2) & 63;
            const int blk = i >> 8;
            const int o   = l & 15;
            unsigned lo = 0, hi = 0;
            {
                int jj = 2 * wj, k = (l >> 4) * 8 + jj;
                int tap = 2 * blk + (k >> 4), c = k & 15;
                if (tap <= 8) {
                    __half hh = __float2half(ker[(o * C_ + c) * KK_ + tap]);
                    lo = __half_as_ushort(hh);
                }
                jj = 2 * wj + 1; k = (l >> 4) * 8 + jj;
                tap = 2 * blk + (k >> 4); c = k & 15;
                if (tap <= 8) {
                    __half hh = __float2half(ker[(o * C_ + c) * KK_ + tap]);
                    hi = __half_as_ushort(hh);
                }
            }
            wsu[KER_OFF + i] = lo | (hi << 16);
        }
    }
}

// ------- tap address/weight setup ------------------------------------------
__device__ __forceinline__ void tap_setup(
    int h, int w, int kk, float dy, float dx,
    int* idx, float* wt)
{
    const float y = dy + (float)(h - 1 + kk / KS_);
    const float x = dx + (float)(w - 1 + kk % KS_);
    const float y0f = floorf(y);
    const float x0f = floorf(x);
    const int   y0  = (int)y0f;
    const int   x0  = (int)x0f;
    const float wy  = y - y0f;
    const float wx  = x - x0f;

    float w00 = (1.f - wy) * (1.f - wx);
    float w01 = (1.f - wy) * wx;
    float w10 = wy * (1.f - wx);
    float w11 = wy * wx;

    const bool v0y = ((unsigned)y0       < (unsigned)H_);
    const bool v1y = ((unsigned)(y0 + 1) < (unsigned)H_);
    const bool v0x = ((unsigned)x0       < (unsigned)W_);
    const bool v1x = ((unsigned)(x0 + 1) < (unsigned)W_);

    wt[0] = (v0y & v0x) ? w00 : 0.f;
    wt[1] = (v0y & v1x) ? w01 : 0.f;
    wt[2] = (v1y & v0x) ? w10 : 0.f;
    wt[3] = (v1y & v1x) ? w11 : 0.f;

    const int y0c = min(max(y0,     0), H_ - 1);
    const int y1c = min(max(y0 + 1, 0), H_ - 1);
    const int x0c = min(max(x0,     0), W_ - 1);
    const int x1c = min(max(x0 + 1, 0), W_ - 1);

    idx[0] = y0c * W_ + x0c;
    idx[1] = y0c * W_ + x1c;
    idx[2] = y1c * W_ + x0c;
    idx[3] = y1c * W_ + x1c;
}

// fp8 corner blend, one output word (2 channels) at a time to keep live
// VGPRs small (stay at the 64-reg occupancy boundary): 4 cvt_pk_f32_fp8 +
// 8 f32 fma + 1 cvt_pkrtz. f32 blend = single rounding; HI selects byte
// pair (template so the builtin's imm constraint is satisfied).
template<bool HI>
__device__ __forceinline__ unsigned blend2_fp8(
    unsigned a, unsigned b, unsigned c, unsigned d,
    float w0, float w1, float w2, float w3)
{
    const f32x2v va = __builtin_amdgcn_cvt_pk_f32_fp8(a, HI);
    const f32x2v vb = __builtin_amdgcn_cvt_pk_f32_fp8(b, HI);
    const f32x2v vc = __builtin_amdgcn_cvt_pk_f32_fp8(c, HI);
    const f32x2v vd = __builtin_amdgcn_cvt_pk_f32_fp8(d, HI);
    const float rl = w0 * va.x + w1 * vb.x + w2 * vc.x + w3 * vd.x;
    const float rh = w0 * va.y + w1 * vb.y + w2 * vc.y + w3 * vd.y;
    union { fp16x2 h; unsigned u; } cv;   // __fp16x2 = cvt_pkrtz return type
    cv.h = __builtin_amdgcn_cvt_pkrtz(rl, rh);
    return cv.u;
}

// ------- Kernel 2: deform-conv + MSE via MFMA, 2 groups/wave, no atomics ---
// Wave = 2 groups x 16 pixels x 4 k-quads. Lane(q=l>>4, m=l&15) holds
// k = q*8+j -> one 8B half of a fp8 NHWC record (was 16B f16 — gather
// stream halves: 335 -> 168 MB, the binding L2 constraint). 5 MFMAs/group.
// Gathers PREFETCHED 2 ITERATIONS AHEAD (3-slot rotation, r7 win).
__global__ __launch_bounds__(256) void deform_loss_mfma(
    const float* __restrict__ off, const unsigned* __restrict__ wsu,
    const float* __restrict__ tgt, float* __restrict__ partials)
{
    // XCD swizzle: bijection on [0,2048); xcd = blk&7 covers 256 consecutive
    // 128-pixel blocks = 128 contiguous rows -> per-XCD L2 locality
    const int f = (blockIdx.x & 7) * 256 + (blockIdx.x >> 3);
    const int t = threadIdx.x;
    const int l = t & 63;
    const int q = l >> 4;
    const int m = l & 15;
    const int base = f * 128 + (t >> 6) * 32;   // wave's 32-pixel span
    const int b    = base >> 16;                // span never crosses b
    const int hwb  = base & (HW_ - 1);
    const int h    = hwb >> 8;                  // same row for both groups
    const int w0   = (hwb & (W_ - 1)) + m;      // group g pixel w = w0+16g

    const float* offp = off + (size_t)b * (2 * KK_ * HW_) + (size_t)h * W_;
    const uint2* ib   = ((const uint2*)wsu) + (size_t)b * HW_ * 2;
    const uint4* kb   = (const uint4*)(wsu + KER_OFF);

    // B-fragments: 5 x 16 B f16, register-resident (unchanged)
    f16x8 bfr[NKB];
#pragma unroll
    for (int kbk = 0; kbk < NKB; kbk++) {
        U4H8 cv; cv.u = kb[kbk * 64 + l];
        bfr[kbk] = cv.h;
    }

    // ALL entry loads issued together: 20 offsets + 2 target float4s.
    // tap>8 clamped to 8: valid memory; contribution zeroed by B=0 padding.
    float dyv[2][NKB], dxv[2][NKB];
#pragma unroll
    for (int g = 0; g < 2; g++)
#pragma unroll
        for (int kbk = 0; kbk < NKB; kbk++) {
            const int tap = min(2 * kbk + (q >> 1), KK_ - 1);
            dyv[g][kbk] = offp[(size_t)(2 * tap) * HW_ + w0 + 16 * g];
            dxv[g][kbk] = offp[(size_t)(2 * tap + 1) * HW_ + w0 + 16 * g];
        }
    // targets (C/D layout: col=lane&15=o, row=4q+reg=pixel-in-group)
    const float* tbase = tgt + (size_t)b * (CO_ * HW_) + (size_t)m * HW_
                       + hwb + 4 * q;
    const float4 tv0 = *(const float4*)(tbase);
    const float4 tv1 = *(const float4*)(tbase + 16);

    f32x4 acc[2] = {{0.f, 0.f, 0.f, 0.f}, {0.f, 0.f, 0.f, 0.f}};
    uint2 cor[3][4];
    float wts[3][4];

    // PREP(KBI, SLOT): tap_setup + pad-collapse + issue 4 corner gathers.
    // K-padding lanes (tap 9, kn==NKB-1 && q>=2): B-frag is 0, so collapse
    // their gathers onto record 0 (broadcast) with wt=0 instead of
    // scattering real clamped-tap-8 gathers.
#define PREP(KBI, SLOT) do {                                               \
        const int gn_ = (KBI) / NKB, kn_ = (KBI) % NKB;                    \
        int idx_[4];                                                       \
        tap_setup(h, w0 + 16 * gn_, min(2 * kn_ + (q >> 1), KK_ - 1),      \
                  dyv[gn_][kn_], dxv[gn_][kn_], idx_, wts[SLOT]);          \
        if (kn_ == NKB - 1 && (q >> 1) != 0) {                             \
            wts[SLOT][0] = 0.f; wts[SLOT][1] = 0.f;                        \
            wts[SLOT][2] = 0.f; wts[SLOT][3] = 0.f;                        \
            idx_[0] = 0; idx_[1] = 0; idx_[2] = 0; idx_[3] = 0;            \
        }                                                                  \
        _Pragma("unroll")                                                  \
        for (int i_ = 0; i_ < 4; i_++)                                     \
            cor[SLOT][i_] = ib[idx_[i_] * 2 + (q & 1)];                    \
    } while (0)

    // prologue: fill slots 0 and 1 (kbi = 0, 1 — never padding blocks)
    PREP(0, 0);
    PREP(1, 1);

#pragma unroll
    for (int kbi = 0; kbi < 2 * NKB; kbi++) {
        const int cur = kbi % 3;
        if (kbi + 2 < 2 * NKB)
            PREP(kbi + 2, (kbi + 2) % 3);

        const int g = kbi / NKB;
        const int kkb = kbi % NKB;
        const float w0_ = wts[cur][0], w1_ = wts[cur][1],
                    w2_ = wts[cur][2], w3_ = wts[cur][3];
        const uint2 c0 = cor[cur][0], c1 = cor[cur][1],
                    c2 = cor[cur][2], c3 = cor[cur][3];
        uint4 A4;
        A4.x = blend2_fp8<false>(c0.x, c1.x, c2.x, c3.x, w0_, w1_, w2_, w3_);
        A4.y = blend2_fp8<true >(c0.x, c1.x, c2.x, c3.x, w0_, w1_, w2_, w3_);
        A4.z = blend2_fp8<false>(c0.y, c1.y, c2.y, c3.y, w0_, w1_, w2_, w3_);
        A4.w = blend2_fp8<true >(c0.y, c1.y, c2.y, c3.y, w0_, w1_, w2_, w3_);
        U4H8 ca; ca.u = A4;

        acc[g] = __builtin_amdgcn_mfma_f32_16x16x32_f16(ca.h, bfr[kkb],
                                                        acc[g], 0, 0, 0);
    }
#undef PREP

    float d0 = acc[0][0] - tv0.x, d1 = acc[0][1] - tv0.y,
          d2 = acc[0][2] - tv0.z, d3 = acc[0][3] - tv0.w;
    float e0 = acc[1][0] - tv1.x, e1 = acc[1][1] - tv1.y,
          e2 = acc[1][2] - tv1.z, e3 = acc[1][3] - tv1.w;
    float part = (d0 * d0 + d1 * d1 + d2 * d2 + d3 * d3
                + e0 * e0 + e1 * e1 + e2 * e2 + e3 * e3)
               * (1.0f / (float)((size_t)B_ * CO_ * HW_));

    // wave reduce -> LDS -> ONE plain store per block (no atomics: grid is
    // exactly 1 round/CU so all 2048 blocks finish together; same-address
    // atomics serialize into a ~6 us burst tail — measured r2)
#pragma unroll
    for (int sft = 32; sft > 0; sft >>= 1)
        part += __shfl_down(part, sft, 64);

    __shared__ float red[4];
    if (l == 0)
        red[t >> 6] = part;
    __syncthreads();
    if (t == 0)
        partials[blockIdx.x] = red[0] + red[1] + red[2] + red[3];
}

// ------- Kernel 3: sum NBLK block partials -> out --------------------------
__global__ __launch_bounds__(256) void reduce_partials(
    const float* __restrict__ partials, float* __restrict__ out)
{
    const int t = threadIdx.x;
    float s = 0.f;
#pragma unroll
    for (int i = 0; i < NBLK / 256; i++)
        s += partials[t + i * 256];
#pragma unroll
    for (int sft = 32; sft > 0; sft >>= 1)
        s += __shfl_down(s, sft, 64);
    __shared__ float red[4];
    if ((t & 63) == 0) red[t >> 6] = s;
    __syncthreads();
    if (t == 0) out[0] = red[0] + red[1] + red[2] + red[3];
}

// ------- Fallback (round-1 NCHW kernel, used if ws too small) --------------
__global__ __launch_bounds__(256) void deform_loss_kernel(
    const float* __restrict__ off, const float* __restrict__ inp,
    const float* __restrict__ ker, const float* __restrict__ tgt,
    float* __restrict__ out)
{
    const int idx = blockIdx.x * blockDim.x + threadIdx.x;
    float part = 0.f;
    if (idx < B_ * H_ * W_) {
        const int w  = idx & (W_ - 1);
        const int h  = (idx >> 8) & (H_ - 1);
        const int b  = idx >> 16;
        const int hw = h * W_ + w;
        const float* offb = off + (size_t)b * (2 * KK_ * HW_);
        const float* inpb = inp + (size_t)b * (C_ * HW_);
        float acc[CO_];
#pragma unroll
        for (int o = 0; o < CO_; o++) acc[o] = 0.f;
        for (int kk = 0; kk < KK_; kk++) {
            const float dy = offb[(2 * kk)     * HW_ + hw];
            const float dx = offb[(2 * kk + 1) * HW_ + hw];
            const float y = dy + (float)(h - 1 + kk / KS_);
            const float x = dx + (float)(w - 1 + kk % KS_);
            const float y0f = floorf(y);
            const float x0f = floorf(x);
            const int   y0  = (int)y0f;
            const int   x0  = (int)x0f;
            const float wy  = y - y0f;
            const float wx  = x - x0f;
            float w00 = (1.f - wy) * (1.f - wx);
            float w01 = (1.f - wy) * wx;
            float w10 = wy * (1.f - wx);
            float w11 = wy * wx;
            const bool v0y = ((unsigned)y0       < (unsigned)H_);
            const bool v1y = ((unsigned)(y0 + 1) < (unsigned)H_);
            const bool v0x = ((unsigned)x0       < (unsigned)W_);
            const bool v1x = ((unsigned)(x0 + 1) < (unsigned)W_);
            w00 = (v0y & v0x) ? w00 : 0.f;
            w01 = (v0y & v1x) ? w01 : 0.f;
            w10 = (v1y & v0x) ? w10 : 0.f;
            w11 = (v1y & v1x) ? w11 : 0.f;
            const int i00 = min(max(y0,0),H_-1)*W_ + min(max(x0,0),W_-1);
            const int i01 = min(max(y0,0),H_-1)*W_ + min(max(x0+1,0),W_-1);
            const int i10 = min(max(y0+1,0),H_-1)*W_ + min(max(x0,0),W_-1);
            const int i11 = min(max(y0+1,0),H_-1)*W_ + min(max(x0+1,0),W_-1);
            for (int c = 0; c < C_; c++) {
                const float* pp = inpb + c * HW_;
                const float s = pp[i00]*w00 + pp[i01]*w01 + pp[i10]*w10 + pp[i11]*w11;
#pragma unroll
                for (int o = 0; o < CO_; o++)
                    acc[o] = fmaf(s, ker[(o * C_ + c) * KK_ + kk], acc[o]);
            }
        }
        const float* tb = tgt + (size_t)b * (CO_ * HW_);
#pragma unroll
        for (int o = 0; o < CO_; o++) {
            const float d = acc[o] - tb[o * HW_ + hw];
            part = fmaf(d, d, part);
        }
        part *= (1.0f / (float)((size_t)B_ * CO_ * HW_));
    }
#pragma unroll
    for (int sft = 32; sft > 0; sft >>= 1)
        part += __shfl_down(part, sft, 64);
    if ((threadIdx.x & 63) == 0)
        atomicAdd(out, part);
}

extern "C" void kernel_launch(void* const* d_in, const int* in_sizes, int n_in,
                              void* d_out, int out_size, void* d_ws, size_t ws_size,
                              hipStream_t stream) {
    const float* offsets = (const float*)d_in[0];
    const float* input   = (const float*)d_in[1];
    const float* ker     = (const float*)d_in[2];
    const float* target  = (const float*)d_in[3];
    float* out = (float*)d_out;

    const size_t need = (PART_OFF + NBLK) * sizeof(unsigned);
    if (ws_size >= need) {
        unsigned* wsu = (unsigned*)d_ws;
        pack_nhwc_fp8<<<(B_ * HW_) / 256, 256, 0, stream>>>(input, ker, wsu);
        // 2048 blocks x 256 threads: wave = 2 groups x 16 pixels x 4 k-quads
        deform_loss_mfma<<<NBLK, 256, 0, stream>>>(
            offsets, wsu, target, (float*)(wsu + PART_OFF));
        reduce_partials<<<1, 256, 0, stream>>>(
            (const float*)(wsu + PART_OFF), out);
    } else {
        hipMemsetAsync(out, 0, sizeof(float), stream);
        const int total = B_ * H_ * W_;
        deform_loss_kernel<<<(total + 255) / 256, 256, 0, stream>>>(
            offsets, input, ker, target, out);
    }
}

// Round 12
// 110.284 us; speedup vs baseline: 1.0121x; 1.0121x over previous
//
#include <hip/hip_runtime.h>
#include <hip/hip_fp16.h>

#define B_  4
#define C_  16
#define H_  256
#define W_  256
#define CO_ 16
#define KS_ 3
#define KK_ 9
#define HW_ (H_ * W_)
// ws layout (u32 words): fp8 image, TWO half-planes of 8 B/pixel | kbuf | parts
#define IMG_WORDS ((size_t)B_ * HW_ * 4)   // 16 B per pixel total (fp8 e4m3)
#define KER_OFF   IMG_WORDS
#define NKB 5                               // k-blocks per group: K=160
#define NBLK 2048                           // blocks: 128 pixels each
#define PART_OFF (KER_OFF + (size_t)NKB * 256)

typedef _Float16 f16x8 __attribute__((ext_vector_type(8)));
typedef __fp16   fp16x2 __attribute__((ext_vector_type(2)));  // cvt_pkrtz ret
typedef float    f32x2v __attribute__((ext_vector_type(2)));
typedef __attribute__((ext_vector_type(4))) float f32x4;
union U4H8 { uint4 u; f16x8 h; };

// 16B load from an 8B-aligned address (pair of adjacent 8B half-records).
// memcpy keeps it defined; gfx9 global loads allow dword alignment, so the
// backend emits a single global_load_dwordx4.
__device__ __forceinline__ uint4 ld16(const uint2* p) {
    uint4 r; __builtin_memcpy(&r, p, sizeof(uint4)); return r;
}

// ------- Kernel 1: NCHW fp32 -> fp8 HALF-PLANE pack + f16 B-frag kernel ----
// Image stored as two planes: plane h holds channels [8h, 8h+8) of every
// pixel, 8 B/pixel contiguous. Adjacent pixels' same-half records are then
// CONTIGUOUS 16 B -> deform fetches each bilinear x-pair with ONE dwordx4
// (transaction-halving; r11 showed bytes don't matter, instructions do).
// Block mapping XCD-aligned with deform (same bx&7 bijection).
__global__ __launch_bounds__(256) void pack_nhwc_fp8(
    const float* __restrict__ inp, const float* __restrict__ ker,
    unsigned* __restrict__ wsu)
{
    const int t = threadIdx.x;
    // bijection on [0,1024): XCD x=bx&7 covers 256-px chunks [x*128,(x+1)*128)
    const int j = (blockIdx.x & 7) * 128 + (blockIdx.x >> 3);
    const int e = j * 256 + t;              // flat pixel (b*HW + hw)
    const int b = e >> 16;
    const int hw = e & (HW_ - 1);
    const float* src = inp + (size_t)b * (C_ * HW_) + hw;
    float v[C_];
#pragma unroll
    for (int c = 0; c < C_; c++)
        v[c] = src[c * HW_];                // coalesced per c-plane
    unsigned u[4];
#pragma unroll
    for (int d = 0; d < 4; d++) {
        unsigned w = 0;
        w = __builtin_amdgcn_cvt_pk_fp8_f32(v[4 * d + 0], v[4 * d + 1], w, false);
        w = __builtin_amdgcn_cvt_pk_fp8_f32(v[4 * d + 2], v[4 * d + 3], w, true);
        u[d] = w;
    }
    uint2* pl = (uint2*)wsu;
    pl[e]                      = make_uint2(u[0], u[1]);   // half 0: ch 0-7
    pl[(size_t)B_ * HW_ + e]   = make_uint2(u[2], u[3]);   // half 1: ch 8-15

    if (blockIdx.x == 0) {
        // kbuf: f16 B-fragment layout for mfma_f32_16x16x32_f16 (unchanged).
        //   B[k][n]: k = (lane>>4)*8 + j, n = o = lane&15,
        //   tap = 2*blk + (k>>4), c = k&15; zero when tap > 8 (K padding).
        for (int i = t; i < NKB * 256; i += 256) {
            const int wj  = i & 3;
            const int l   = (i >> 2) & 63;
            const int blk = i >> 8;
            const int o   = l & 15;
            unsigned lo = 0, hi = 0;
            {
                int jj = 2 * wj, k = (l >> 4) * 8 + jj;
                int tap = 2 * blk + (k >> 4), c = k & 15;
                if (tap <= 8) {
                    __half hh = __float2half(ker[(o * C_ + c) * KK_ + tap]);
                    lo = __half_as_ushort(hh);
                }
                jj = 2 * wj + 1; k = (l >> 4) * 8 + jj;
                tap = 2 * blk + (k >> 4); c = k & 15;
                if (tap <= 8) {
                    __half hh = __float2half(ker[(o * C_ + c) * KK_ + tap]);
                    hi = __half_as_ushort(hh);
                }
            }
            wsu[KER_OFF + i] = lo | (hi << 16);
        }
    }
}

// ------- tap setup, pair form ----------------------------------------------
// Loads x-pair records [p, p+1] per row, p = clamp(x0, 0, W-2). Both clamped
// corners always land on slot lo (p) or hi (p+1); edge cases route the
// corner weights to the right slot (identical arithmetic to the 4-corner
// form — absmax unchanged). wt = {lo_top, hi_top, lo_bot, hi_bot}.
__device__ __forceinline__ void tap_setup_pair(
    int h, int w, int kk, float dy, float dx,
    int* ridx, float* wt)
{
    const float y = dy + (float)(h - 1 + kk / KS_);
    const float x = dx + (float)(w - 1 + kk % KS_);
    const float y0f = floorf(y);
    const float x0f = floorf(x);
    const int   y0  = (int)y0f;
    const int   x0  = (int)x0f;
    const float wy  = y - y0f;
    const float wx  = x - x0f;

    float w00 = (1.f - wy) * (1.f - wx);
    float w01 = (1.f - wy) * wx;
    float w10 = wy * (1.f - wx);
    float w11 = wy * wx;

    const bool v0y = ((unsigned)y0       < (unsigned)H_);
    const bool v1y = ((unsigned)(y0 + 1) < (unsigned)H_);
    const bool v0x = ((unsigned)x0       < (unsigned)W_);
    const bool v1x = ((unsigned)(x0 + 1) < (unsigned)W_);

    w00 = (v0y & v0x) ? w00 : 0.f;
    w01 = (v0y & v1x) ? w01 : 0.f;
    w10 = (v1y & v0x) ? w10 : 0.f;
    w11 = (v1y & v1x) ? w11 : 0.f;

    const int  p    = min(max(x0, 0), W_ - 2);
    const bool s0hi = (x0 >= W_ - 1);   // corner x0   -> hi slot (right edge)
    const bool s1lo = (x0 <= -1);       // corner x0+1 -> lo slot (left edge)

    wt[0] = (s0hi ? 0.f : w00) + (s1lo ? w01 : 0.f);
    wt[1] = (s0hi ? w00 : 0.f) + (s1lo ? 0.f : w01);
    wt[2] = (s0hi ? 0.f : w10) + (s1lo ? w11 : 0.f);
    wt[3] = (s0hi ? w10 : 0.f) + (s1lo ? 0.f : w11);

    const int y0c = min(max(y0,     0), H_ - 1);
    const int y1c = min(max(y0 + 1, 0), H_ - 1);
    ridx[0] = y0c * W_ + p;
    ridx[1] = y1c * W_ + p;
}

// fp8 corner blend, one output word (2 channels): 4 cvt_pk_f32_fp8 +
// 8 f32 fma + 1 cvt_pkrtz. f32 blend = single rounding.
template<bool HI>
__device__ __forceinline__ unsigned blend2_fp8(
    unsigned a, unsigned b, unsigned c, unsigned d,
    float w0, float w1, float w2, float w3)
{
    const f32x2v va = __builtin_amdgcn_cvt_pk_f32_fp8(a, HI);
    const f32x2v vb = __builtin_amdgcn_cvt_pk_f32_fp8(b, HI);
    const f32x2v vc = __builtin_amdgcn_cvt_pk_f32_fp8(c, HI);
    const f32x2v vd = __builtin_amdgcn_cvt_pk_f32_fp8(d, HI);
    const float rl = w0 * va.x + w1 * vb.x + w2 * vc.x + w3 * vd.x;
    const float rh = w0 * va.y + w1 * vb.y + w2 * vc.y + w3 * vd.y;
    union { fp16x2 h; unsigned u; } cv;
    cv.h = __builtin_amdgcn_cvt_pkrtz(rl, rh);
    return cv.u;
}

// ------- Kernel 2: deform-conv + MSE via MFMA, 2 groups/wave, no atomics ---
// Wave = 2 groups x 16 pixels x 4 k-quads. Lane(q,m) reads its channel-half
// plane; each bilinear x-pair is ONE dwordx4 (2 gathers/tap vs 4 — the
// r11 lesson: transaction count, not bytes, bounds this kernel).
// Gathers PREFETCHED 2 ITERATIONS AHEAD (3-slot rotation, r7 win).
__global__ __launch_bounds__(256) void deform_loss_mfma(
    const float* __restrict__ off, const unsigned* __restrict__ wsu,
    const float* __restrict__ tgt, float* __restrict__ partials)
{
    // XCD swizzle: bijection on [0,2048); xcd = blk&7 covers 256 consecutive
    // 128-pixel blocks = 128 contiguous rows -> per-XCD L2 locality
    const int f = (blockIdx.x & 7) * 256 + (blockIdx.x >> 3);
    const int t = threadIdx.x;
    const int l = t & 63;
    const int q = l >> 4;
    const int m = l & 15;
    const int base = f * 128 + (t >> 6) * 32;   // wave's 32-pixel span
    const int b    = base >> 16;                // span never crosses b
    const int hwb  = base & (HW_ - 1);
    const int h    = hwb >> 8;                  // same row for both groups
    const int w0   = (hwb & (W_ - 1)) + m;      // group g pixel w = w0+16g

    const float* offp = off + (size_t)b * (2 * KK_ * HW_) + (size_t)h * W_;
    const uint2* ibh  = (const uint2*)wsu
                      + (size_t)(q & 1) * (B_ * HW_) + (size_t)b * HW_;
    const uint4* kb   = (const uint4*)(wsu + KER_OFF);

    // B-fragments: 5 x 16 B f16, register-resident (unchanged)
    f16x8 bfr[NKB];
#pragma unroll
    for (int kbk = 0; kbk < NKB; kbk++) {
        U4H8 cv; cv.u = kb[kbk * 64 + l];
        bfr[kbk] = cv.h;
    }

    // ALL entry loads issued together: 20 offsets + 2 target float4s.
    // tap>8 clamped to 8: valid memory; contribution zeroed by B=0 padding.
    float dyv[2][NKB], dxv[2][NKB];
#pragma unroll
    for (int g = 0; g < 2; g++)
#pragma unroll
        for (int kbk = 0; kbk < NKB; kbk++) {
            const int tap = min(2 * kbk + (q >> 1), KK_ - 1);
            dyv[g][kbk] = offp[(size_t)(2 * tap) * HW_ + w0 + 16 * g];
            dxv[g][kbk] = offp[(size_t)(2 * tap + 1) * HW_ + w0 + 16 * g];
        }
    // targets (C/D layout: col=lane&15=o, row=4q+reg=pixel-in-group)
    const float* tbase = tgt + (size_t)b * (CO_ * HW_) + (size_t)m * HW_
                       + hwb + 4 * q;
    const float4 tv0 = *(const float4*)(tbase);
    const float4 tv1 = *(const float4*)(tbase + 16);

    f32x4 acc[2] = {{0.f, 0.f, 0.f, 0.f}, {0.f, 0.f, 0.f, 0.f}};
    uint4 cor[3][2];        // [slot][row]: .xy = lo record, .zw = hi record
    float wts[3][4];

    // PREP(KBI, SLOT): tap_setup_pair + pad-collapse + 2 dwordx4 gathers.
    // K-padding lanes (tap 9, kn==NKB-1 && q>=2): B-frag is 0, so collapse
    // their gathers onto records 0-1 (broadcast) with wt=0.
#define PREP(KBI, SLOT) do {                                               \
        const int gn_ = (KBI) / NKB, kn_ = (KBI) % NKB;                    \
        int ridx_[2];                                                      \
        tap_setup_pair(h, w0 + 16 * gn_, min(2 * kn_ + (q >> 1), KK_ - 1), \
                       dyv[gn_][kn_], dxv[gn_][kn_], ridx_, wts[SLOT]);    \
        if (kn_ == NKB - 1 && (q >> 1) != 0) {                             \
            wts[SLOT][0] = 0.f; wts[SLOT][1] = 0.f;                        \
            wts[SLOT][2] = 0.f; wts[SLOT][3] = 0.f;                        \
            ridx_[0] = 0; ridx_[1] = 0;                                    \
        }                                                                  \
        cor[SLOT][0] = ld16(ibh + ridx_[0]);                               \
        cor[SLOT][1] = ld16(ibh + ridx_[1]);                               \
    } while (0)

    // prologue: fill slots 0 and 1 (kbi = 0, 1 — never padding blocks)
    PREP(0, 0);
    PREP(1, 1);

#pragma unroll
    for (int kbi = 0; kbi < 2 * NKB; kbi++) {
        const int cur = kbi % 3;
        if (kbi + 2 < 2 * NKB)
            PREP(kbi + 2, (kbi + 2) % 3);

        const int g = kbi / NKB;
        const int kkb = kbi % NKB;
        const float wlt = wts[cur][0], wht = wts[cur][1],
                    wlb = wts[cur][2], whb = wts[cur][3];
        const uint4 ct = cor[cur][0];   // top row pair
        const uint4 cb = cor[cur][1];   // bottom row pair
        uint4 A4;
        A4.x = blend2_fp8<false>(ct.x, ct.z, cb.x, cb.z, wlt, wht, wlb, whb);
        A4.y = blend2_fp8<true >(ct.x, ct.z, cb.x, cb.z, wlt, wht, wlb, whb);
        A4.z = blend2_fp8<false>(ct.y, ct.w, cb.y, cb.w, wlt, wht, wlb, whb);
        A4.w = blend2_fp8<true >(ct.y, ct.w, cb.y, cb.w, wlt, wht, wlb, whb);
        U4H8 ca; ca.u = A4;

        acc[g] = __builtin_amdgcn_mfma_f32_16x16x32_f16(ca.h, bfr[kkb],
                                                        acc[g], 0, 0, 0);
    }
#undef PREP

    float d0 = acc[0][0] - tv0.x, d1 = acc[0][1] - tv0.y,
          d2 = acc[0][2] - tv0.z, d3 = acc[0][3] - tv0.w;
    float e0 = acc[1][0] - tv1.x, e1 = acc[1][1] - tv1.y,
          e2 = acc[1][2] - tv1.z, e3 = acc[1][3] - tv1.w;
    float part = (d0 * d0 + d1 * d1 + d2 * d2 + d3 * d3
                + e0 * e0 + e1 * e1 + e2 * e2 + e3 * e3)
               * (1.0f / (float)((size_t)B_ * CO_ * HW_));

    // wave reduce -> LDS -> ONE plain store per block (no atomics: grid is
    // exactly 1 round/CU so all 2048 blocks finish together; same-address
    // atomics serialize into a ~6 us burst tail — measured r2)
#pragma unroll
    for (int sft = 32; sft > 0; sft >>= 1)
        part += __shfl_down(part, sft, 64);

    __shared__ float red[4];
    if (l == 0)
        red[t >> 6] = part;
    __syncthreads();
    if (t == 0)
        partials[blockIdx.x] = red[0] + red[1] + red[2] + red[3];
}

// ------- Kernel 3: sum NBLK block partials -> out --------------------------
__global__ __launch_bounds__(256) void reduce_partials(
    const float* __restrict__ partials, float* __restrict__ out)
{
    const int t = threadIdx.x;
    float s = 0.f;
#pragma unroll
    for (int i = 0; i < NBLK / 256; i++)
        s += partials[t + i * 256];
#pragma unroll
    for (int sft = 32; sft > 0; sft >>= 1)
        s += __shfl_down(s, sft, 64);
    __shared__ float red[4];
    if ((t & 63) == 0) red[t >> 6] = s;
    __syncthreads();
    if (t == 0) out[0] = red[0] + red[1] + red[2] + red[3];
}

// ------- Fallback (round-1 NCHW kernel, used if ws too small) --------------
__global__ __launch_bounds__(256) void deform_loss_kernel(
    const float* __restrict__ off, const float* __restrict__ inp,
    const float* __restrict__ ker, const float* __restrict__ tgt,
    float* __restrict__ out)
{
    const int idx = blockIdx.x * blockDim.x + threadIdx.x;
    float part = 0.f;
    if (idx < B_ * H_ * W_) {
        const int w  = idx & (W_ - 1);
        const int h  = (idx >> 8) & (H_ - 1);
        const int b  = idx >> 16;
        const int hw = h * W_ + w;
        const float* offb = off + (size_t)b * (2 * KK_ * HW_);
        const float* inpb = inp + (size_t)b * (C_ * HW_);
        float acc[CO_];
#pragma unroll
        for (int o = 0; o < CO_; o++) acc[o] = 0.f;
        for (int kk = 0; kk < KK_; kk++) {
            const float dy = offb[(2 * kk)     * HW_ + hw];
            const float dx = offb[(2 * kk + 1) * HW_ + hw];
            const float y = dy + (float)(h - 1 + kk / KS_);
            const float x = dx + (float)(w - 1 + kk % KS_);
            const float y0f = floorf(y);
            const float x0f = floorf(x);
            const int   y0  = (int)y0f;
            const int   x0  = (int)x0f;
            const float wy  = y - y0f;
            const float wx  = x - x0f;
            float w00 = (1.f - wy) * (1.f - wx);
            float w01 = (1.f - wy) * wx;
            float w10 = wy * (1.f - wx);
            float w11 = wy * wx;
            const bool v0y = ((unsigned)y0       < (unsigned)H_);
            const bool v1y = ((unsigned)(y0 + 1) < (unsigned)H_);
            const bool v0x = ((unsigned)x0       < (unsigned)W_);
            const bool v1x = ((unsigned)(x0 + 1) < (unsigned)W_);
            w00 = (v0y & v0x) ? w00 : 0.f;
            w01 = (v0y & v1x) ? w01 : 0.f;
            w10 = (v1y & v0x) ? w10 : 0.f;
            w11 = (v1y & v1x) ? w11 : 0.f;
            const int i00 = min(max(y0,0),H_-1)*W_ + min(max(x0,0),W_-1);
            const int i01 = min(max(y0,0),H_-1)*W_ + min(max(x0+1,0),W_-1);
            const int i10 = min(max(y0+1,0),H_-1)*W_ + min(max(x0,0),W_-1);
            const int i11 = min(max(y0+1,0),H_-1)*W_ + min(max(x0+1,0),W_-1);
            for (int c = 0; c < C_; c++) {
                const float* pp = inpb + c * HW_;
                const float s = pp[i00]*w00 + pp[i01]*w01 + pp[i10]*w10 + pp[i11]*w11;
#pragma unroll
                for (int o = 0; o < CO_; o++)
                    acc[o] = fmaf(s, ker[(o * C_ + c) * KK_ + kk], acc[o]);
            }
        }
        const float* tb = tgt + (size_t)b * (CO_ * HW_);
#pragma unroll
        for (int o = 0; o < CO_; o++) {
            const float d = acc[o] - tb[o * HW_ + hw];
            part = fmaf(d, d, part);
        }
        part *= (1.0f / (float)((size_t)B_ * CO_ * HW_));
    }
#pragma unroll
    for (int sft = 32; sft > 0; sft >>= 1)
        part += __shfl_down(part, sft, 64);
    if ((threadIdx.x & 63) == 0)
        atomicAdd(out, part);
}

extern "C" void kernel_launch(void* const* d_in, const int* in_sizes, int n_in,
                              void* d_out, int out_size, void* d_ws, size_t ws_size,
                              hipStream_t stream) {
    const float* offsets = (const float*)d_in[0];
    const float* input   = (const float*)d_in[1];
    const float* ker     = (const float*)d_in[2];
    const float* target  = (const float*)d_in[3];
    float* out = (float*)d_out;

    const size_t need = (PART_OFF + NBLK) * sizeof(unsigned);
    if (ws_size >= need) {
        unsigned* wsu = (unsigned*)d_ws;
        pack_nhwc_fp8<<<(B_ * HW_) / 256, 256, 0, stream>>>(input, ker, wsu);
        // 2048 blocks x 256 threads: wave = 2 groups x 16 pixels x 4 k-quads
        deform_loss_mfma<<<NBLK, 256, 0, stream>>>(
            offsets, wsu, target, (float*)(wsu + PART_OFF));
        reduce_partials<<<1, 256, 0, stream>>>(
            (const float*)(wsu + PART_OFF), out);
    } else {
        hipMemsetAsync(out, 0, sizeof(float), stream);
        const int total = B_ * H_ * W_;
        deform_loss_kernel<<<(total + 255) / 256, 256, 0, stream>>>(
            offsets, input, ker, target, out);
    }
}